// Round 5
// baseline (1480.198 us; speedup 1.0000x reference)
//
#include <hip/hip_runtime.h>

typedef unsigned short u16;
typedef __attribute__((ext_vector_type(8))) short bf16x8;
typedef __attribute__((ext_vector_type(4))) float f32x4;

#define B_ 4
#define D_ 1024
#define N_ 1024
#define H_ 16
#define DK_ 64

__device__ inline float bf2f(u16 x) {
    union { unsigned u; float f; } c; c.u = ((unsigned)x) << 16; return c.f;
}
__device__ inline u16 f2bf(float f) {
    union { float f; unsigned u; } c; c.f = f;
    unsigned r = c.u + 0x7fff + ((c.u >> 16) & 1);
    return (u16)(r >> 16);
}

#if __has_builtin(__builtin_amdgcn_exp2f)
#define EXP2(x) __builtin_amdgcn_exp2f(x)
#else
#define EXP2(x) __expf((x) * 0.6931471805599453f)
#endif

// fl=1 -> storage fp32 (convert on load), fl=0 -> bf16
__device__ inline bf16x8 load8(const void* p, size_t idx, int fl) {
    if (!fl) return *(const bf16x8*)((const u16*)p + idx);
    const float* fp = (const float*)p + idx;
    f32x4 a = *(const f32x4*)fp;
    f32x4 b = *(const f32x4*)(fp + 4);
    bf16x8 r;
    #pragma unroll
    for (int j = 0; j < 4; ++j) {
        ((u16*)&r)[j]     = f2bf(a[j]);
        ((u16*)&r)[4 + j] = f2bf(b[j]);
    }
    return r;
}

// fp32 -> bf16 bulk convert, 8 elems/thread
__global__ __launch_bounds__(256) void k_cvt(
    const float* __restrict__ src, u16* __restrict__ dst, int n8)
{
    int i = blockIdx.x * 256 + threadIdx.x;
    if (i < n8) {
        const f32x4* s = (const f32x4*)src;
        f32x4 a = s[2 * i], b = s[2 * i + 1];
        bf16x8 r;
        #pragma unroll
        for (int j = 0; j < 4; ++j) {
            ((u16*)&r)[j]     = f2bf(a[j]);
            ((u16*)&r)[4 + j] = f2bf(b[j]);
        }
        ((bf16x8*)dst)[i] = r;
    }
}

// ---------------------------------------------------------------------------
// Pipelined GEMM core (unchanged from R4): D[m][n] = sum_k A[m][k]*Bt[n][k]
// ---------------------------------------------------------------------------
template<int MT, int NT>
__device__ inline void gemm_core(const u16* __restrict__ A, int lda,
                                 const void* __restrict__ Bt, size_t eoff,
                                 int ldb, int fl,
                                 int K, int m0, int n0,
                                 u16* lds, f32x4 acc[MT/32][NT/32])
{
    constexpr int FM = MT / 32, FN = NT / 32;
    constexpr int CA = MT * 4 / 256, CB = NT * 4 / 256;
    const int tid  = threadIdx.x;
    const int wave = tid >> 6, lane = tid & 63;
    const int quad = lane >> 4, l15 = lane & 15;
    const int wm = (wave >> 1) * (MT / 2);
    const int wn = (wave & 1) * (NT / 2);

    int arow[CA], acol[CA], brow[CB], bcol[CB];
    #pragma unroll
    for (int i = 0; i < CA; ++i) { int x = tid + i * 256; arow[i] = x >> 2; acol[i] = (x & 3) << 3; }
    #pragma unroll
    for (int i = 0; i < CB; ++i) { int x = tid + i * 256; brow[i] = x >> 2; bcol[i] = (x & 3) << 3; }

    bf16x8 pa[CA], pb[CB];
    #pragma unroll
    for (int i = 0; i < CA; ++i)
        pa[i] = *(const bf16x8*)(A + (size_t)(m0 + arow[i]) * lda + acol[i]);
    #pragma unroll
    for (int i = 0; i < CB; ++i)
        pb[i] = load8(Bt, eoff + (size_t)(n0 + brow[i]) * ldb + bcol[i], fl);

    int buf = 0;
    for (int k0 = 0; k0 < K; k0 += 32) {
        u16* La = lds + buf * ((MT + NT) * 40);
        u16* Lb = La + MT * 40;
        #pragma unroll
        for (int i = 0; i < CA; ++i) *(bf16x8*)&La[arow[i] * 40 + acol[i]] = pa[i];
        #pragma unroll
        for (int i = 0; i < CB; ++i) *(bf16x8*)&Lb[brow[i] * 40 + bcol[i]] = pb[i];
        __syncthreads();

        if (k0 + 32 < K) {
            #pragma unroll
            for (int i = 0; i < CA; ++i)
                pa[i] = *(const bf16x8*)(A + (size_t)(m0 + arow[i]) * lda + k0 + 32 + acol[i]);
            #pragma unroll
            for (int i = 0; i < CB; ++i)
                pb[i] = load8(Bt, eoff + (size_t)(n0 + brow[i]) * ldb + k0 + 32 + bcol[i], fl);
        }

        bf16x8 af[FM], bv[FN];
        #pragma unroll
        for (int f = 0; f < FM; ++f)
            af[f] = *(bf16x8*)&La[(wm + f * 16 + l15) * 40 + quad * 8];
        #pragma unroll
        for (int f = 0; f < FN; ++f)
            bv[f] = *(bf16x8*)&Lb[(wn + f * 16 + l15) * 40 + quad * 8];
        #pragma unroll
        for (int fm = 0; fm < FM; ++fm)
            #pragma unroll
            for (int fn = 0; fn < FN; ++fn)
                acc[fm][fn] = __builtin_amdgcn_mfma_f32_16x16x32_bf16(
                    af[fm], bv[fn], acc[fm][fn], 0, 0, 0);
        buf ^= 1;
    }
}

#define EPI_SETUP \
    const int tid = threadIdx.x; \
    const int wave = tid >> 6, lane = tid & 63; \
    const int quad = lane >> 4, l15 = lane & 15;

// ---------------------------------------------------------------------------
// K1: QKV. z = mat (0=q,1=k,2=v). A = xb [4096][1024].
// q,k -> [bh][pos][dk]; v -> [bh][dk][pos]
// ---------------------------------------------------------------------------
__global__ __launch_bounds__(256) void k_qkv(
    const u16* __restrict__ xb,
    const void* __restrict__ Wq, const void* __restrict__ Wk, const void* __restrict__ Wv,
    const float* __restrict__ bq, const float* __restrict__ bk, const float* __restrict__ bv,
    int fl, u16* __restrict__ qh, u16* __restrict__ kh, u16* __restrict__ vt)
{
    __shared__ u16 lds[2 * (128 + 128) * 40];
    int mat = blockIdx.z;
    const void* W     = mat == 0 ? Wq : (mat == 1 ? Wk : Wv);
    const float* bias = mat == 0 ? bq : (mat == 1 ? bk : bv);
    int m0 = blockIdx.x * 128, n0 = blockIdx.y * 128;

    f32x4 acc[4][4];
    #pragma unroll
    for (int i = 0; i < 4; ++i)
        #pragma unroll
        for (int j = 0; j < 4; ++j) acc[i][j] = f32x4{0.f, 0.f, 0.f, 0.f};

    gemm_core<128, 128>(xb, D_, W, 0, D_, fl, D_, m0, n0, lds, acc);

    EPI_SETUP
    const int wm = (wave >> 1) * 64, wn = (wave & 1) * 64;
    #pragma unroll
    for (int fm = 0; fm < 4; ++fm)
        #pragma unroll
        for (int fn = 0; fn < 4; ++fn) {
            int n = n0 + wn + fn * 16 + l15;
            float bz = bias[n];
            int h = n & 15, dk = n >> 4;
            #pragma unroll
            for (int r = 0; r < 4; ++r) {
                int m = m0 + wm + fm * 16 + quad * 4 + r;
                int b = m >> 10, pos = m & 1023;
                u16 o = f2bf(acc[fm][fn][r] + bz);
                if (mat == 0)
                    qh[(((size_t)(b * H_ + h) * N_ + pos) * DK_ + dk)] = o;
                else if (mat == 1)
                    kh[(((size_t)(b * H_ + h) * N_ + pos) * DK_ + dk)] = o;
                else
                    vt[(((size_t)(b * H_ + h) * DK_ + dk) * N_ + pos)] = o;
            }
        }
}

// ---------------------------------------------------------------------------
// K2: barrier-free flash attention. Grid (16, 64): 64 q-rows per block,
// 16 q-rows per wave. K/V fragments read DIRECTLY from global (B-frag
// order, L2-served); only the wave-private P transpose uses LDS (m120).
// No __syncthreads anywhere -> waves fully self-overlap.
// ---------------------------------------------------------------------------
__global__ __launch_bounds__(256) void k_flash(
    const u16* __restrict__ qh, const u16* __restrict__ kh,
    const u16* __restrict__ vt, u16* __restrict__ at)
{
    __shared__ u16 ldsP[4 * 16 * 136];   // per-wave P tile [16 q][128 kv], pad 136

    const int bh = blockIdx.y, b = bh >> 4, h = bh & 15;
    const int tid = threadIdx.x, wave = tid >> 6, lane = tid & 63;
    const int quad = lane >> 4, l15 = lane & 15;
    const int q0 = blockIdx.x * 64 + wave * 16;   // this wave's q-row base

    const u16* Q = qh + (size_t)bh * N_ * DK_;
    const u16* K = kh + (size_t)bh * N_ * DK_;
    const u16* V = vt + (size_t)bh * DK_ * N_;
    u16* P = ldsP + wave * 16 * 136;

    // Q fragments: A[m=l15][k=quad*8+j], held all kernel
    bf16x8 qf[2];
    #pragma unroll
    for (int kk = 0; kk < 2; ++kk)
        qf[kk] = *(const bf16x8*)&Q[(size_t)(q0 + l15) * DK_ + kk * 32 + quad * 8];

    f32x4 acc_o[4];
    #pragma unroll
    for (int j = 0; j < 4; ++j) acc_o[j] = f32x4{0.f, 0.f, 0.f, 0.f};
    float mrow[4], lrow[4];
    #pragma unroll
    for (int r = 0; r < 4; ++r) { mrow[r] = -1e30f; lrow[r] = 0.f; }

    const float c = 0.18033688011112042f;  // 0.125 * log2(e)

    for (int mt = 0; mt < 8; ++mt) {
        // S = Q.K^T : 16 q-rows x 128 kv-cols
        f32x4 s[8];
        #pragma unroll
        for (int j = 0; j < 8; ++j) s[j] = f32x4{0.f, 0.f, 0.f, 0.f};
        #pragma unroll
        for (int kk = 0; kk < 2; ++kk) {
            bf16x8 kf[8];
            #pragma unroll
            for (int fn = 0; fn < 8; ++fn)
                kf[fn] = *(const bf16x8*)&K[(size_t)(mt * 128 + fn * 16 + l15) * DK_
                                            + kk * 32 + quad * 8];
            #pragma unroll
            for (int fn = 0; fn < 8; ++fn)
                s[fn] = __builtin_amdgcn_mfma_f32_16x16x32_bf16(
                    qf[kk], kf[fn], s[fn], 0, 0, 0);
        }

        // online softmax on raw scores; exp(s/8 - m/8) = 2^((s-m)*c)
        #pragma unroll
        for (int r = 0; r < 4; ++r) {
            float mx = s[0][r];
            #pragma unroll
            for (int fn = 1; fn < 8; ++fn) mx = fmaxf(mx, s[fn][r]);
            #pragma unroll
            for (int o = 1; o < 16; o <<= 1)
                mx = fmaxf(mx, __shfl_xor(mx, o, 64));
            float mn = fmaxf(mrow[r], mx);
            float al = EXP2((mrow[r] - mn) * c);
            float nmc = -mn * c;
            float rs = 0.f;
            #pragma unroll
            for (int fn = 0; fn < 8; ++fn) {
                float p = EXP2(fmaf(s[fn][r], c, nmc));
                s[fn][r] = p;
                rs += p;
            }
            #pragma unroll
            for (int o = 1; o < 16; o <<= 1)
                rs += __shfl_xor(rs, o, 64);
            lrow[r] = al * lrow[r] + rs;
            mrow[r] = mn;
            #pragma unroll
            for (int fn = 0; fn < 4; ++fn) acc_o[fn][r] *= al;
        }

        // P -> wave-private LDS (C-layout -> A-layout round trip)
        #pragma unroll
        for (int fn = 0; fn < 8; ++fn)
            #pragma unroll
            for (int r = 0; r < 4; ++r)
                P[(quad * 4 + r) * 136 + fn * 16 + l15] = f2bf(s[fn][r]);

        // P.V: pf from LDS (lgkm-ordered by compiler), vf direct from global
        #pragma unroll
        for (int ks = 0; ks < 4; ++ks) {
            bf16x8 vf[4];
            #pragma unroll
            for (int fn = 0; fn < 4; ++fn)
                vf[fn] = *(const bf16x8*)&V[(size_t)(fn * 16 + l15) * N_
                                            + mt * 128 + ks * 32 + quad * 8];
            bf16x8 pf = *(bf16x8*)&P[l15 * 136 + ks * 32 + quad * 8];
            #pragma unroll
            for (int fn = 0; fn < 4; ++fn)
                acc_o[fn] = __builtin_amdgcn_mfma_f32_16x16x32_bf16(
                    pf, vf[fn], acc_o[fn], 0, 0, 0);
        }
    }

    // epilogue: O /= l, write at[b][pos][dk*16+h]
    #pragma unroll
    for (int r = 0; r < 4; ++r) {
        float inv = 1.f / lrow[r];
        int pos = q0 + quad * 4 + r;
        #pragma unroll
        for (int fn = 0; fn < 4; ++fn) {
            int dk = fn * 16 + l15;
            at[((size_t)(b * N_ + pos)) * D_ + dk * 16 + h] =
                f2bf(acc_o[fn][r] * inv);
        }
    }
}

// ---------------------------------------------------------------------------
// K3: merged = Wm . attn + bm.  MT=64,NT=128, grid (64,8).
// ---------------------------------------------------------------------------
__global__ __launch_bounds__(256) void k_merged(
    const u16* __restrict__ at, const void* __restrict__ Wm,
    const float* __restrict__ bm, int fl, u16* __restrict__ mg)
{
    __shared__ u16 lds[2 * (64 + 128) * 40];
    int m0 = blockIdx.x * 64, n0 = blockIdx.y * 128;

    f32x4 acc[2][4];
    #pragma unroll
    for (int i = 0; i < 2; ++i)
        #pragma unroll
        for (int j = 0; j < 4; ++j) acc[i][j] = f32x4{0.f, 0.f, 0.f, 0.f};

    gemm_core<64, 128>(at, D_, Wm, 0, D_, fl, D_, m0, n0, lds, acc);

    EPI_SETUP
    const int wm = (wave >> 1) * 32, wn = (wave & 1) * 64;
    #pragma unroll
    for (int fm = 0; fm < 2; ++fm)
        #pragma unroll
        for (int fn = 0; fn < 4; ++fn) {
            int n = n0 + wn + fn * 16 + l15;
            float bz = bm[n];
            #pragma unroll
            for (int r = 0; r < 4; ++r) {
                int m = m0 + wm + fm * 16 + quad * 4 + r;
                mg[(size_t)m * D_ + n] = f2bf(acc[fm][fn][r] + bz);
            }
        }
}

// ---------------------------------------------------------------------------
// K4: h2 = relu(BN(Wp1 . [merged; x] + bp1)): two accumulating K-passes.
// ---------------------------------------------------------------------------
__global__ __launch_bounds__(256) void k_p1(
    const u16* __restrict__ mg, const u16* __restrict__ xb,
    const void* __restrict__ Wp1, int fl,
    const float* __restrict__ bp1, const float* __restrict__ gam,
    const float* __restrict__ bet, const float* __restrict__ mu,
    const float* __restrict__ var, u16* __restrict__ h2)
{
    __shared__ u16 lds[2 * (128 + 128) * 40];
    int m0 = blockIdx.x * 128, n0 = blockIdx.y * 128;

    f32x4 acc[4][4];
    #pragma unroll
    for (int i = 0; i < 4; ++i)
        #pragma unroll
        for (int j = 0; j < 4; ++j) acc[i][j] = f32x4{0.f, 0.f, 0.f, 0.f};

    gemm_core<128, 128>(mg, D_, Wp1, 0,    2048, fl, D_, m0, n0, lds, acc);
    gemm_core<128, 128>(xb, D_, Wp1, 1024, 2048, fl, D_, m0, n0, lds, acc);

    EPI_SETUP
    const int wm = (wave >> 1) * 64, wn = (wave & 1) * 64;
    #pragma unroll
    for (int fm = 0; fm < 4; ++fm)
        #pragma unroll
        for (int fn = 0; fn < 4; ++fn) {
            int n = n0 + wn + fn * 16 + l15;
            float bz = bp1[n];
            float sc = gam[n] * rsqrtf(var[n] + 1e-5f);
            float mn = mu[n], be = bet[n];
            #pragma unroll
            for (int r = 0; r < 4; ++r) {
                int m = m0 + wm + fm * 16 + quad * 4 + r;
                float y = (acc[fm][fn][r] + bz - mn) * sc + be;
                h2[(size_t)m * 2048 + n] = f2bf(fmaxf(y, 0.f));
            }
        }
}

// ---------------------------------------------------------------------------
// K5: x += Wp2 . h2 + bp2.  MT=64,NT=128, grid (64,8).
// ---------------------------------------------------------------------------
__global__ __launch_bounds__(256) void k_p2(
    const u16* __restrict__ h2, const void* __restrict__ Wp2,
    const float* __restrict__ bp2, int fl,
    float* __restrict__ xf, u16* __restrict__ xb)
{
    __shared__ u16 lds[2 * (64 + 128) * 40];
    int m0 = blockIdx.x * 64, n0 = blockIdx.y * 128;

    f32x4 acc[2][4];
    #pragma unroll
    for (int i = 0; i < 2; ++i)
        #pragma unroll
        for (int j = 0; j < 4; ++j) acc[i][j] = f32x4{0.f, 0.f, 0.f, 0.f};

    gemm_core<64, 128>(h2, 2048, Wp2, 0, 2048, fl, 2048, m0, n0, lds, acc);

    EPI_SETUP
    const int wm = (wave >> 1) * 32, wn = (wave & 1) * 64;
    #pragma unroll
    for (int fm = 0; fm < 2; ++fm)
        #pragma unroll
        for (int fn = 0; fn < 4; ++fn) {
            int n = n0 + wn + fn * 16 + l15;
            float bz = bp2[n];
            #pragma unroll
            for (int r = 0; r < 4; ++r) {
                int m = m0 + wm + fm * 16 + quad * 4 + r;
                size_t ad = (size_t)m * D_ + n;
                float nv = xf[ad] + acc[fm][fn][r] + bz;
                xf[ad] = nv;
                xb[ad] = f2bf(nv);
            }
        }
}

// K0: transpose motion (b,c,pos) fp32 -> xf/xb [b][pos][c]
__global__ __launch_bounds__(256) void k_tin(
    const float* __restrict__ mo, float* __restrict__ xf, u16* __restrict__ xb)
{
    __shared__ float t[32][33];
    int b = blockIdx.z;
    int p0 = blockIdx.x * 32, c0 = blockIdx.y * 32;
    int tx = threadIdx.x & 31, ty = threadIdx.x >> 5;
    const float* src = mo + ((size_t)b * D_ + c0) * N_ + p0;
    #pragma unroll
    for (int k = 0; k < 4; ++k)
        t[ty + k * 8][tx] = src[(size_t)(ty + k * 8) * N_ + tx];
    __syncthreads();
    size_t base = ((size_t)b * N_ + p0) * D_ + c0;
    #pragma unroll
    for (int k = 0; k < 4; ++k) {
        float v = t[tx][ty + k * 8];
        xf[base + (size_t)(ty + k * 8) * D_ + tx] = v;
        xb[base + (size_t)(ty + k * 8) * D_ + tx] = f2bf(v);
    }
}

// K6: transpose back, fp32 out
__global__ __launch_bounds__(256) void k_tout(
    const float* __restrict__ xf, float* __restrict__ out)
{
    __shared__ float t[32][33];
    int b = blockIdx.z;
    int c0 = blockIdx.x * 32, p0 = blockIdx.y * 32;
    int tx = threadIdx.x & 31, ty = threadIdx.x >> 5;
    const float* src = xf + ((size_t)b * N_ + p0) * D_ + c0;
    #pragma unroll
    for (int k = 0; k < 4; ++k)
        t[ty + k * 8][tx] = src[(size_t)(ty + k * 8) * D_ + tx];
    __syncthreads();
    float* dst = out + ((size_t)b * D_ + c0) * N_ + p0;
    #pragma unroll
    for (int k = 0; k < 4; ++k)
        dst[(size_t)(ty + k * 8) * N_ + tx] = t[tx][ty + k * 8];
}

extern "C" void kernel_launch(void* const* d_in, const int* in_sizes, int n_in,
                              void* d_out, int out_size, void* d_ws, size_t ws_size,
                              hipStream_t stream)
{
    const float* mo  = (const float*)d_in[0];
    const float* Wqf = (const float*)d_in[1];
    const float* bq  = (const float*)d_in[2];
    const float* Wkf = (const float*)d_in[3];
    const float* bk  = (const float*)d_in[4];
    const float* Wvf = (const float*)d_in[5];
    const float* bv  = (const float*)d_in[6];
    const float* Wmf = (const float*)d_in[7];
    const float* bm  = (const float*)d_in[8];
    const float* Wp1f= (const float*)d_in[9];
    const float* bp1 = (const float*)d_in[10];
    const float* gam = (const float*)d_in[11];
    const float* bet = (const float*)d_in[12];
    const float* mu  = (const float*)d_in[13];
    const float* var = (const float*)d_in[14];
    const float* Wp2f= (const float*)d_in[15];
    const float* bp2 = (const float*)d_in[16];

    char* ws = (char*)d_ws;
    float* xf = (float*)ws;                       //  0-16 MB fp32 residual
    u16* xb   = (u16*)(ws + (16ull << 20));       // 16-24
    u16* qh   = (u16*)(ws + (24ull << 20));       // 24-32 ; later mg
    u16* kh   = (u16*)(ws + (32ull << 20));       // 32-40 ; later h2 (spans kh+vt)
    u16* vt   = (u16*)(ws + (40ull << 20));       // 40-48
    u16* at   = (u16*)(ws + (48ull << 20));       // 48-56
    u16* mg   = qh;
    u16* h2   = kh;
    u16* wb   = (u16*)(ws + (56ull << 20));       // bf16 weight cache

    const size_t S1 = 1048576;      // one D*D matrix
    const size_t SP1 = 4194304;     // one 2048*2048
    const size_t SP2 = 2097152;     // one 1024*2048
    const size_t OQ = 0, OK4 = 4 * S1, OV = 8 * S1, OM = 12 * S1,
                 OP1 = 16 * S1, OP2 = OP1 + 4 * SP1;

    int mode;  // 2 = convert all layers (80MB), 1 = per-layer (20MB), 0 = fp32 direct
    if (ws_size >= (137ull << 20)) mode = 2;
    else if (ws_size >= (77ull << 20)) mode = 1;
    else mode = 0;
    const int fl = (mode == 0) ? 1 : 0;

    dim3 blk(256);
    if (mode == 2) {
        k_cvt<<<2048, blk, 0, stream>>>(Wqf,  wb + OQ,  524288);
        k_cvt<<<2048, blk, 0, stream>>>(Wkf,  wb + OK4, 524288);
        k_cvt<<<2048, blk, 0, stream>>>(Wvf,  wb + OV,  524288);
        k_cvt<<<2048, blk, 0, stream>>>(Wmf,  wb + OM,  524288);
        k_cvt<<<8192, blk, 0, stream>>>(Wp1f, wb + OP1, 2097152);
        k_cvt<<<4096, blk, 0, stream>>>(Wp2f, wb + OP2, 1048576);
    }

    k_tin<<<dim3(32, 32, 4), blk, 0, stream>>>(mo, xf, xb);

    for (int l = 0; l < 4; ++l) {
        const void *pWq, *pWk, *pWv, *pWm, *pWp1, *pWp2;
        if (mode == 2) {
            pWq  = wb + OQ  + (size_t)l * S1;
            pWk  = wb + OK4 + (size_t)l * S1;
            pWv  = wb + OV  + (size_t)l * S1;
            pWm  = wb + OM  + (size_t)l * S1;
            pWp1 = wb + OP1 + (size_t)l * SP1;
            pWp2 = wb + OP2 + (size_t)l * SP2;
        } else if (mode == 1) {
            k_cvt<<<512,  blk, 0, stream>>>(Wqf  + l * S1,  wb,               131072);
            k_cvt<<<512,  blk, 0, stream>>>(Wkf  + l * S1,  wb + S1,          131072);
            k_cvt<<<512,  blk, 0, stream>>>(Wvf  + l * S1,  wb + 2 * S1,      131072);
            k_cvt<<<512,  blk, 0, stream>>>(Wmf  + l * S1,  wb + 3 * S1,      131072);
            k_cvt<<<2048, blk, 0, stream>>>(Wp1f + l * SP1, wb + 4 * S1,      524288);
            k_cvt<<<1024, blk, 0, stream>>>(Wp2f + l * SP2, wb + 4 * S1 + SP1, 262144);
            pWq = wb; pWk = wb + S1; pWv = wb + 2 * S1; pWm = wb + 3 * S1;
            pWp1 = wb + 4 * S1; pWp2 = wb + 4 * S1 + SP1;
        } else {
            pWq  = Wqf  + l * S1;
            pWk  = Wkf  + l * S1;
            pWv  = Wvf  + l * S1;
            pWm  = Wmf  + l * S1;
            pWp1 = Wp1f + l * SP1;
            pWp2 = Wp2f + l * SP2;
        }

        k_qkv<<<dim3(32, 8, 3), blk, 0, stream>>>(
            xb, pWq, pWk, pWv, bq + l * D_, bk + l * D_, bv + l * D_, fl, qh, kh, vt);
        k_flash<<<dim3(16, 64), blk, 0, stream>>>(qh, kh, vt, at);
        k_merged<<<dim3(64, 8), blk, 0, stream>>>(at, pWm, bm + l * D_, fl, mg);
        k_p1<<<dim3(32, 16), blk, 0, stream>>>(
            mg, xb, pWp1, fl, bp1 + l * 2048, gam + l * 2048, bet + l * 2048,
            mu + l * 2048, var + l * 2048, h2);
        k_p2<<<dim3(64, 8), blk, 0, stream>>>(
            h2, pWp2, bp2 + l * D_, fl, xf, xb);
    }
    k_tout<<<dim3(32, 32, 4), blk, 0, stream>>>(xf, (float*)d_out);
}

// Round 6
// 1274.087 us; speedup vs baseline: 1.1618x; 1.1618x over previous
//
#include <hip/hip_runtime.h>

typedef unsigned short u16;
typedef __attribute__((ext_vector_type(8))) short bf16x8;
typedef __attribute__((ext_vector_type(4))) float f32x4;

#define B_ 4
#define D_ 1024
#define N_ 1024
#define H_ 16
#define DK_ 64

__device__ inline float bf2f(u16 x) {
    union { unsigned u; float f; } c; c.u = ((unsigned)x) << 16; return c.f;
}
__device__ inline u16 f2bf(float f) {
    union { float f; unsigned u; } c; c.f = f;
    unsigned r = c.u + 0x7fff + ((c.u >> 16) & 1);
    return (u16)(r >> 16);
}

#if __has_builtin(__builtin_amdgcn_exp2f)
#define EXP2(x) __builtin_amdgcn_exp2f(x)
#else
#define EXP2(x) __expf((x) * 0.6931471805599453f)
#endif

// fl=1 -> storage fp32 (convert on load), fl=0 -> bf16
__device__ inline bf16x8 load8(const void* p, size_t idx, int fl) {
    if (!fl) return *(const bf16x8*)((const u16*)p + idx);
    const float* fp = (const float*)p + idx;
    f32x4 a = *(const f32x4*)fp;
    f32x4 b = *(const f32x4*)(fp + 4);
    bf16x8 r;
    #pragma unroll
    for (int j = 0; j < 4; ++j) {
        ((u16*)&r)[j]     = f2bf(a[j]);
        ((u16*)&r)[4 + j] = f2bf(b[j]);
    }
    return r;
}

// fp32 -> bf16 bulk convert, 8 elems/thread
__global__ __launch_bounds__(256) void k_cvt(
    const float* __restrict__ src, u16* __restrict__ dst, int n8)
{
    int i = blockIdx.x * 256 + threadIdx.x;
    if (i < n8) {
        const f32x4* s = (const f32x4*)src;
        f32x4 a = s[2 * i], b = s[2 * i + 1];
        bf16x8 r;
        #pragma unroll
        for (int j = 0; j < 4; ++j) {
            ((u16*)&r)[j]     = f2bf(a[j]);
            ((u16*)&r)[4 + j] = f2bf(b[j]);
        }
        ((bf16x8*)dst)[i] = r;
    }
}

// ---------------------------------------------------------------------------
// Pipelined GEMM core: D[m][n] = sum_k A[m][k]*Bt[n][k]
// ---------------------------------------------------------------------------
template<int MT, int NT>
__device__ inline void gemm_core(const u16* __restrict__ A, int lda,
                                 const void* __restrict__ Bt, size_t eoff,
                                 int ldb, int fl,
                                 int K, int m0, int n0,
                                 u16* lds, f32x4 acc[MT/32][NT/32])
{
    constexpr int FM = MT / 32, FN = NT / 32;
    constexpr int CA = MT * 4 / 256, CB = NT * 4 / 256;
    const int tid  = threadIdx.x;
    const int wave = tid >> 6, lane = tid & 63;
    const int quad = lane >> 4, l15 = lane & 15;
    const int wm = (wave >> 1) * (MT / 2);
    const int wn = (wave & 1) * (NT / 2);

    int arow[CA], acol[CA], brow[CB], bcol[CB];
    #pragma unroll
    for (int i = 0; i < CA; ++i) { int x = tid + i * 256; arow[i] = x >> 2; acol[i] = (x & 3) << 3; }
    #pragma unroll
    for (int i = 0; i < CB; ++i) { int x = tid + i * 256; brow[i] = x >> 2; bcol[i] = (x & 3) << 3; }

    bf16x8 pa[CA], pb[CB];
    #pragma unroll
    for (int i = 0; i < CA; ++i)
        pa[i] = *(const bf16x8*)(A + (size_t)(m0 + arow[i]) * lda + acol[i]);
    #pragma unroll
    for (int i = 0; i < CB; ++i)
        pb[i] = load8(Bt, eoff + (size_t)(n0 + brow[i]) * ldb + bcol[i], fl);

    int buf = 0;
    for (int k0 = 0; k0 < K; k0 += 32) {
        u16* La = lds + buf * ((MT + NT) * 40);
        u16* Lb = La + MT * 40;
        #pragma unroll
        for (int i = 0; i < CA; ++i) *(bf16x8*)&La[arow[i] * 40 + acol[i]] = pa[i];
        #pragma unroll
        for (int i = 0; i < CB; ++i) *(bf16x8*)&Lb[brow[i] * 40 + bcol[i]] = pb[i];
        __syncthreads();

        if (k0 + 32 < K) {
            #pragma unroll
            for (int i = 0; i < CA; ++i)
                pa[i] = *(const bf16x8*)(A + (size_t)(m0 + arow[i]) * lda + k0 + 32 + acol[i]);
            #pragma unroll
            for (int i = 0; i < CB; ++i)
                pb[i] = load8(Bt, eoff + (size_t)(n0 + brow[i]) * ldb + k0 + 32 + bcol[i], fl);
        }

        bf16x8 af[FM], bv[FN];
        #pragma unroll
        for (int f = 0; f < FM; ++f)
            af[f] = *(bf16x8*)&La[(wm + f * 16 + l15) * 40 + quad * 8];
        #pragma unroll
        for (int f = 0; f < FN; ++f)
            bv[f] = *(bf16x8*)&Lb[(wn + f * 16 + l15) * 40 + quad * 8];
        #pragma unroll
        for (int fm = 0; fm < FM; ++fm)
            #pragma unroll
            for (int fn = 0; fn < FN; ++fn)
                acc[fm][fn] = __builtin_amdgcn_mfma_f32_16x16x32_bf16(
                    af[fm], bv[fn], acc[fm][fn], 0, 0, 0);
        buf ^= 1;
    }
}

#define EPI_SETUP \
    const int tid = threadIdx.x; \
    const int wave = tid >> 6, lane = tid & 63; \
    const int quad = lane >> 4, l15 = lane & 15;

// ---------------------------------------------------------------------------
// K1: QKV. z = mat (0=q,1=k,2=v). A = xb [4096][1024].
// q -> [bh][pos][dk] (row-major)
// k -> FRAGMENT layout: [bh][g=pos>>4][kk=dk>>5][quad=(dk>>3)&3][l15=pos&15][j=dk&7]
// v -> FRAGMENT layout: [bh][c=pos>>5][fn=dk>>4][quad=(pos>>3)&3][l15=dk&15][j=pos&7]
// so k_flash's kf/vf wave-loads are 64x16B fully contiguous (8 cache lines).
// ---------------------------------------------------------------------------
__global__ __launch_bounds__(256) void k_qkv(
    const u16* __restrict__ xb,
    const void* __restrict__ Wq, const void* __restrict__ Wk, const void* __restrict__ Wv,
    const float* __restrict__ bq, const float* __restrict__ bk, const float* __restrict__ bv,
    int fl, u16* __restrict__ qh, u16* __restrict__ kh, u16* __restrict__ vt)
{
    __shared__ u16 lds[2 * (128 + 128) * 40];
    int mat = blockIdx.z;
    const void* W     = mat == 0 ? Wq : (mat == 1 ? Wk : Wv);
    const float* bias = mat == 0 ? bq : (mat == 1 ? bk : bv);
    int m0 = blockIdx.x * 128, n0 = blockIdx.y * 128;

    f32x4 acc[4][4];
    #pragma unroll
    for (int i = 0; i < 4; ++i)
        #pragma unroll
        for (int j = 0; j < 4; ++j) acc[i][j] = f32x4{0.f, 0.f, 0.f, 0.f};

    gemm_core<128, 128>(xb, D_, W, 0, D_, fl, D_, m0, n0, lds, acc);

    EPI_SETUP
    const int wm = (wave >> 1) * 64, wn = (wave & 1) * 64;
    #pragma unroll
    for (int fm = 0; fm < 4; ++fm)
        #pragma unroll
        for (int fn = 0; fn < 4; ++fn) {
            int n = n0 + wn + fn * 16 + l15;
            float bz = bias[n];
            int h = n & 15, dk = n >> 4;
            #pragma unroll
            for (int r = 0; r < 4; ++r) {
                int m = m0 + wm + fm * 16 + quad * 4 + r;
                int b = m >> 10, pos = m & 1023;
                int bh = b * H_ + h;
                u16 o = f2bf(acc[fm][fn][r] + bz);
                if (mat == 0) {
                    qh[(((size_t)bh * N_ + pos) * DK_ + dk)] = o;
                } else if (mat == 1) {
                    size_t kidx = (((size_t)bh * 64 + (pos >> 4)) << 10)
                                + ((dk >> 5) << 9) + (((dk >> 3) & 3) << 7)
                                + ((pos & 15) << 3) + (dk & 7);
                    kh[kidx] = o;
                } else {
                    size_t vidx = (((size_t)bh * 32 + (pos >> 5)) << 11)
                                + ((dk >> 4) << 9) + (((pos >> 3) & 3) << 7)
                                + ((dk & 15) << 3) + (pos & 7);
                    vt[vidx] = o;
                }
            }
        }
}

// ---------------------------------------------------------------------------
// K2: barrier-free flash attention, ONE WAVE PER BLOCK (64 thr).
// Grid (64, 64): 16 q-rows per block/wave -> 4096 blocks, ~16 blocks/CU.
// K/V read from fragment-contiguous layouts (fully coalesced 1KB loads).
// Only the wave-private P transpose uses LDS. No __syncthreads.
// ---------------------------------------------------------------------------
__global__ __launch_bounds__(64) void k_flash(
    const u16* __restrict__ qh, const u16* __restrict__ kh,
    const u16* __restrict__ vt, u16* __restrict__ at)
{
    __shared__ u16 P[16 * 136];   // P tile [16 q][128 kv], pad 136

    const int bh = blockIdx.y, b = bh >> 4, h = bh & 15;
    const int lane = threadIdx.x;
    const int quad = lane >> 4, l15 = lane & 15;
    const int q0 = blockIdx.x * 16;

    const u16* Q  = qh + (size_t)bh * N_ * DK_;
    const u16* Kf = kh + ((size_t)bh << 16);
    const u16* Vf = vt + ((size_t)bh << 16);

    // Q fragments: A[m=l15][k=quad*8+j], held all kernel
    bf16x8 qf[2];
    #pragma unroll
    for (int kk = 0; kk < 2; ++kk)
        qf[kk] = *(const bf16x8*)&Q[(size_t)(q0 + l15) * DK_ + kk * 32 + quad * 8];

    f32x4 acc_o[4];
    #pragma unroll
    for (int j = 0; j < 4; ++j) acc_o[j] = f32x4{0.f, 0.f, 0.f, 0.f};
    float mrow[4], lrow[4];
    #pragma unroll
    for (int r = 0; r < 4; ++r) { mrow[r] = -1e30f; lrow[r] = 0.f; }

    const float c = 0.18033688011112042f;  // 0.125 * log2(e)

    #pragma unroll 2
    for (int mt = 0; mt < 8; ++mt) {
        // S = Q.K^T : 16 q-rows x 128 kv-cols
        f32x4 s[8];
        #pragma unroll
        for (int j = 0; j < 8; ++j) s[j] = f32x4{0.f, 0.f, 0.f, 0.f};
        #pragma unroll
        for (int kk = 0; kk < 2; ++kk) {
            bf16x8 kf[8];
            #pragma unroll
            for (int fn = 0; fn < 8; ++fn)
                kf[fn] = *(const bf16x8*)&Kf[((size_t)(mt * 8 + fn) << 10)
                                             + (kk << 9) + (quad << 7) + (l15 << 3)];
            #pragma unroll
            for (int fn = 0; fn < 8; ++fn)
                s[fn] = __builtin_amdgcn_mfma_f32_16x16x32_bf16(
                    qf[kk], kf[fn], s[fn], 0, 0, 0);
        }

        // online softmax; exp(s/8 - m/8) = 2^((s-m)*c)
        #pragma unroll
        for (int r = 0; r < 4; ++r) {
            float mx = s[0][r];
            #pragma unroll
            for (int fn = 1; fn < 8; ++fn) mx = fmaxf(mx, s[fn][r]);
            #pragma unroll
            for (int o = 1; o < 16; o <<= 1)
                mx = fmaxf(mx, __shfl_xor(mx, o, 64));
            float mn = fmaxf(mrow[r], mx);
            float al = EXP2((mrow[r] - mn) * c);
            float nmc = -mn * c;
            float rs = 0.f;
            #pragma unroll
            for (int fn = 0; fn < 8; ++fn) {
                float p = EXP2(fmaf(s[fn][r], c, nmc));
                s[fn][r] = p;
                rs += p;
            }
            #pragma unroll
            for (int o = 1; o < 16; o <<= 1)
                rs += __shfl_xor(rs, o, 64);
            lrow[r] = al * lrow[r] + rs;
            mrow[r] = mn;
            #pragma unroll
            for (int fn = 0; fn < 4; ++fn) acc_o[fn][r] *= al;
        }

        // P -> LDS (C-layout -> A-layout round trip)
        #pragma unroll
        for (int fn = 0; fn < 8; ++fn)
            #pragma unroll
            for (int r = 0; r < 4; ++r)
                P[(quad * 4 + r) * 136 + fn * 16 + l15] = f2bf(s[fn][r]);

        // P.V: pf from LDS, vf from fragment-contiguous global
        #pragma unroll
        for (int ks = 0; ks < 4; ++ks) {
            bf16x8 vf[4];
            #pragma unroll
            for (int fn = 0; fn < 4; ++fn)
                vf[fn] = *(const bf16x8*)&Vf[((size_t)(mt * 4 + ks) << 11)
                                             + (fn << 9) + (quad << 7) + (l15 << 3)];
            bf16x8 pf = *(bf16x8*)&P[l15 * 136 + ks * 32 + quad * 8];
            #pragma unroll
            for (int fn = 0; fn < 4; ++fn)
                acc_o[fn] = __builtin_amdgcn_mfma_f32_16x16x32_bf16(
                    pf, vf[fn], acc_o[fn], 0, 0, 0);
        }
    }

    // epilogue: O /= l, write at[b][pos][dk*16+h]
    #pragma unroll
    for (int r = 0; r < 4; ++r) {
        float inv = 1.f / lrow[r];
        int pos = q0 + quad * 4 + r;
        #pragma unroll
        for (int fn = 0; fn < 4; ++fn) {
            int dk = fn * 16 + l15;
            at[((size_t)(b * N_ + pos)) * D_ + dk * 16 + h] =
                f2bf(acc_o[fn][r] * inv);
        }
    }
}

// ---------------------------------------------------------------------------
// K3: merged = Wm . attn + bm.  MT=64,NT=128, grid (64,8).
// ---------------------------------------------------------------------------
__global__ __launch_bounds__(256) void k_merged(
    const u16* __restrict__ at, const void* __restrict__ Wm,
    const float* __restrict__ bm, int fl, u16* __restrict__ mg)
{
    __shared__ u16 lds[2 * (64 + 128) * 40];
    int m0 = blockIdx.x * 64, n0 = blockIdx.y * 128;

    f32x4 acc[2][4];
    #pragma unroll
    for (int i = 0; i < 2; ++i)
        #pragma unroll
        for (int j = 0; j < 4; ++j) acc[i][j] = f32x4{0.f, 0.f, 0.f, 0.f};

    gemm_core<64, 128>(at, D_, Wm, 0, D_, fl, D_, m0, n0, lds, acc);

    EPI_SETUP
    const int wm = (wave >> 1) * 32, wn = (wave & 1) * 64;
    #pragma unroll
    for (int fm = 0; fm < 2; ++fm)
        #pragma unroll
        for (int fn = 0; fn < 4; ++fn) {
            int n = n0 + wn + fn * 16 + l15;
            float bz = bm[n];
            #pragma unroll
            for (int r = 0; r < 4; ++r) {
                int m = m0 + wm + fm * 16 + quad * 4 + r;
                mg[(size_t)m * D_ + n] = f2bf(acc[fm][fn][r] + bz);
            }
        }
}

// ---------------------------------------------------------------------------
// K4: h2 = relu(BN(Wp1 . [merged; x] + bp1)): two accumulating K-passes.
// ---------------------------------------------------------------------------
__global__ __launch_bounds__(256) void k_p1(
    const u16* __restrict__ mg, const u16* __restrict__ xb,
    const void* __restrict__ Wp1, int fl,
    const float* __restrict__ bp1, const float* __restrict__ gam,
    const float* __restrict__ bet, const float* __restrict__ mu,
    const float* __restrict__ var, u16* __restrict__ h2)
{
    __shared__ u16 lds[2 * (128 + 128) * 40];
    int m0 = blockIdx.x * 128, n0 = blockIdx.y * 128;

    f32x4 acc[4][4];
    #pragma unroll
    for (int i = 0; i < 4; ++i)
        #pragma unroll
        for (int j = 0; j < 4; ++j) acc[i][j] = f32x4{0.f, 0.f, 0.f, 0.f};

    gemm_core<128, 128>(mg, D_, Wp1, 0,    2048, fl, D_, m0, n0, lds, acc);
    gemm_core<128, 128>(xb, D_, Wp1, 1024, 2048, fl, D_, m0, n0, lds, acc);

    EPI_SETUP
    const int wm = (wave >> 1) * 64, wn = (wave & 1) * 64;
    #pragma unroll
    for (int fm = 0; fm < 4; ++fm)
        #pragma unroll
        for (int fn = 0; fn < 4; ++fn) {
            int n = n0 + wn + fn * 16 + l15;
            float bz = bp1[n];
            float sc = gam[n] * rsqrtf(var[n] + 1e-5f);
            float mn = mu[n], be = bet[n];
            #pragma unroll
            for (int r = 0; r < 4; ++r) {
                int m = m0 + wm + fm * 16 + quad * 4 + r;
                float y = (acc[fm][fn][r] + bz - mn) * sc + be;
                h2[(size_t)m * 2048 + n] = f2bf(fmaxf(y, 0.f));
            }
        }
}

// ---------------------------------------------------------------------------
// K5: x += Wp2 . h2 + bp2.  MT=64,NT=128, grid (64,8).
// ---------------------------------------------------------------------------
__global__ __launch_bounds__(256) void k_p2(
    const u16* __restrict__ h2, const void* __restrict__ Wp2,
    const float* __restrict__ bp2, int fl,
    float* __restrict__ xf, u16* __restrict__ xb)
{
    __shared__ u16 lds[2 * (64 + 128) * 40];
    int m0 = blockIdx.x * 64, n0 = blockIdx.y * 128;

    f32x4 acc[2][4];
    #pragma unroll
    for (int i = 0; i < 2; ++i)
        #pragma unroll
        for (int j = 0; j < 4; ++j) acc[i][j] = f32x4{0.f, 0.f, 0.f, 0.f};

    gemm_core<64, 128>(h2, 2048, Wp2, 0, 2048, fl, 2048, m0, n0, lds, acc);

    EPI_SETUP
    const int wm = (wave >> 1) * 32, wn = (wave & 1) * 64;
    #pragma unroll
    for (int fm = 0; fm < 2; ++fm)
        #pragma unroll
        for (int fn = 0; fn < 4; ++fn) {
            int n = n0 + wn + fn * 16 + l15;
            float bz = bp2[n];
            #pragma unroll
            for (int r = 0; r < 4; ++r) {
                int m = m0 + wm + fm * 16 + quad * 4 + r;
                size_t ad = (size_t)m * D_ + n;
                float nv = xf[ad] + acc[fm][fn][r] + bz;
                xf[ad] = nv;
                xb[ad] = f2bf(nv);
            }
        }
}

// K0: transpose motion (b,c,pos) fp32 -> xf/xb [b][pos][c]
__global__ __launch_bounds__(256) void k_tin(
    const float* __restrict__ mo, float* __restrict__ xf, u16* __restrict__ xb)
{
    __shared__ float t[32][33];
    int b = blockIdx.z;
    int p0 = blockIdx.x * 32, c0 = blockIdx.y * 32;
    int tx = threadIdx.x & 31, ty = threadIdx.x >> 5;
    const float* src = mo + ((size_t)b * D_ + c0) * N_ + p0;
    #pragma unroll
    for (int k = 0; k < 4; ++k)
        t[ty + k * 8][tx] = src[(size_t)(ty + k * 8) * N_ + tx];
    __syncthreads();
    size_t base = ((size_t)b * N_ + p0) * D_ + c0;
    #pragma unroll
    for (int k = 0; k < 4; ++k) {
        float v = t[tx][ty + k * 8];
        xf[base + (size_t)(ty + k * 8) * D_ + tx] = v;
        xb[base + (size_t)(ty + k * 8) * D_ + tx] = f2bf(v);
    }
}

// K6: transpose back, fp32 out
__global__ __launch_bounds__(256) void k_tout(
    const float* __restrict__ xf, float* __restrict__ out)
{
    __shared__ float t[32][33];
    int b = blockIdx.z;
    int c0 = blockIdx.x * 32, p0 = blockIdx.y * 32;
    int tx = threadIdx.x & 31, ty = threadIdx.x >> 5;
    const float* src = xf + ((size_t)b * N_ + p0) * D_ + c0;
    #pragma unroll
    for (int k = 0; k < 4; ++k)
        t[ty + k * 8][tx] = src[(size_t)(ty + k * 8) * D_ + tx];
    __syncthreads();
    float* dst = out + ((size_t)b * D_ + c0) * N_ + p0;
    #pragma unroll
    for (int k = 0; k < 4; ++k)
        dst[(size_t)(ty + k * 8) * N_ + tx] = t[tx][ty + k * 8];
}

extern "C" void kernel_launch(void* const* d_in, const int* in_sizes, int n_in,
                              void* d_out, int out_size, void* d_ws, size_t ws_size,
                              hipStream_t stream)
{
    const float* mo  = (const float*)d_in[0];
    const float* Wqf = (const float*)d_in[1];
    const float* bq  = (const float*)d_in[2];
    const float* Wkf = (const float*)d_in[3];
    const float* bk  = (const float*)d_in[4];
    const float* Wvf = (const float*)d_in[5];
    const float* bv  = (const float*)d_in[6];
    const float* Wmf = (const float*)d_in[7];
    const float* bm  = (const float*)d_in[8];
    const float* Wp1f= (const float*)d_in[9];
    const float* bp1 = (const float*)d_in[10];
    const float* gam = (const float*)d_in[11];
    const float* bet = (const float*)d_in[12];
    const float* mu  = (const float*)d_in[13];
    const float* var = (const float*)d_in[14];
    const float* Wp2f= (const float*)d_in[15];
    const float* bp2 = (const float*)d_in[16];

    char* ws = (char*)d_ws;
    float* xf = (float*)ws;                       //  0-16 MB fp32 residual
    u16* xb   = (u16*)(ws + (16ull << 20));       // 16-24
    u16* qh   = (u16*)(ws + (24ull << 20));       // 24-32 ; later mg
    u16* kh   = (u16*)(ws + (32ull << 20));       // 32-40 ; later h2 (spans kh+vt)
    u16* vt   = (u16*)(ws + (40ull << 20));       // 40-48
    u16* at   = (u16*)(ws + (48ull << 20));       // 48-56
    u16* mg   = qh;
    u16* h2   = kh;
    u16* wb   = (u16*)(ws + (56ull << 20));       // bf16 weight cache

    const size_t S1 = 1048576;      // one D*D matrix
    const size_t SP1 = 4194304;     // one 2048*2048
    const size_t SP2 = 2097152;     // one 1024*2048
    const size_t OQ = 0, OK4 = 4 * S1, OV = 8 * S1, OM = 12 * S1,
                 OP1 = 16 * S1, OP2 = OP1 + 4 * SP1;

    int mode;  // 2 = convert all layers (80MB), 1 = per-layer (20MB), 0 = fp32 direct
    if (ws_size >= (137ull << 20)) mode = 2;
    else if (ws_size >= (77ull << 20)) mode = 1;
    else mode = 0;
    const int fl = (mode == 0) ? 1 : 0;

    dim3 blk(256);
    if (mode == 2) {
        k_cvt<<<2048, blk, 0, stream>>>(Wqf,  wb + OQ,  524288);
        k_cvt<<<2048, blk, 0, stream>>>(Wkf,  wb + OK4, 524288);
        k_cvt<<<2048, blk, 0, stream>>>(Wvf,  wb + OV,  524288);
        k_cvt<<<2048, blk, 0, stream>>>(Wmf,  wb + OM,  524288);
        k_cvt<<<8192, blk, 0, stream>>>(Wp1f, wb + OP1, 2097152);
        k_cvt<<<4096, blk, 0, stream>>>(Wp2f, wb + OP2, 1048576);
    }

    k_tin<<<dim3(32, 32, 4), blk, 0, stream>>>(mo, xf, xb);

    for (int l = 0; l < 4; ++l) {
        const void *pWq, *pWk, *pWv, *pWm, *pWp1, *pWp2;
        if (mode == 2) {
            pWq  = wb + OQ  + (size_t)l * S1;
            pWk  = wb + OK4 + (size_t)l * S1;
            pWv  = wb + OV  + (size_t)l * S1;
            pWm  = wb + OM  + (size_t)l * S1;
            pWp1 = wb + OP1 + (size_t)l * SP1;
            pWp2 = wb + OP2 + (size_t)l * SP2;
        } else if (mode == 1) {
            k_cvt<<<512,  blk, 0, stream>>>(Wqf  + l * S1,  wb,               131072);
            k_cvt<<<512,  blk, 0, stream>>>(Wkf  + l * S1,  wb + S1,          131072);
            k_cvt<<<512,  blk, 0, stream>>>(Wvf  + l * S1,  wb + 2 * S1,      131072);
            k_cvt<<<512,  blk, 0, stream>>>(Wmf  + l * S1,  wb + 3 * S1,      131072);
            k_cvt<<<2048, blk, 0, stream>>>(Wp1f + l * SP1, wb + 4 * S1,      524288);
            k_cvt<<<1024, blk, 0, stream>>>(Wp2f + l * SP2, wb + 4 * S1 + SP1, 262144);
            pWq = wb; pWk = wb + S1; pWv = wb + 2 * S1; pWm = wb + 3 * S1;
            pWp1 = wb + 4 * S1; pWp2 = wb + 4 * S1 + SP1;
        } else {
            pWq  = Wqf  + l * S1;
            pWk  = Wkf  + l * S1;
            pWv  = Wvf  + l * S1;
            pWm  = Wmf  + l * S1;
            pWp1 = Wp1f + l * SP1;
            pWp2 = Wp2f + l * SP2;
        }

        k_qkv<<<dim3(32, 8, 3), blk, 0, stream>>>(
            xb, pWq, pWk, pWv, bq + l * D_, bk + l * D_, bv + l * D_, fl, qh, kh, vt);
        k_flash<<<dim3(64, 64), dim3(64), 0, stream>>>(qh, kh, vt, at);
        k_merged<<<dim3(64, 8), blk, 0, stream>>>(at, pWm, bm + l * D_, fl, mg);
        k_p1<<<dim3(32, 16), blk, 0, stream>>>(
            mg, xb, pWp1, fl, bp1 + l * 2048, gam + l * 2048, bet + l * 2048,
            mu + l * 2048, var + l * 2048, h2);
        k_p2<<<dim3(64, 8), blk, 0, stream>>>(
            h2, pWp2, bp2 + l * D_, fl, xf, xb);
    }
    k_tout<<<dim3(32, 32, 4), blk, 0, stream>>>(xf, (float*)d_out);
}